// Round 4
// baseline (241.629 us; speedup 1.0000x reference)
//
#include <hip/hip_runtime.h>

// B=32, T=2048, D=1024 (fp32)
// out[b,d] = sum_t softmax_t(tanh(x[b,t,:]·W + bias[t])) * x[b,t,d]
// tanh in (-1,1) -> exp never overflows -> single pass, no max subtraction.
//
// Per-wave private LDS double-buffer streamed with global_load_lds + counted
// vmcnt (never drained to 0 in the loop). No arrays in registers (round-3
// post-mortem: lambda+array staging went to scratch, VGPR=68, 5x regression).

#define PSTR 1032  // floats per partial: [0]=lsum, [8..1032)=acc[1024]

typedef const __attribute__((address_space(1))) void* gas_ptr;
typedef __attribute__((address_space(3))) void* las_ptr;

__global__ __launch_bounds__(256) void fused_all(
    const float* __restrict__ x, const float* __restrict__ w,
    const float* __restrict__ bias, float* __restrict__ partials,
    unsigned int* __restrict__ counters, float* __restrict__ out,
    int T, int C)
{
    const int c = blockIdx.x;          // T-chunk (64 rows)
    const int b = blockIdx.y;          // batch
    const int wv = threadIdx.x >> 6;
    const int lane = threadIdx.x & 63;
    const int tid = threadIdx.x;

    const int rows_block = T / C;              // 64
    const int rows_wave  = rows_block >> 2;    // 16
    const int r0 = c * rows_block + wv * rows_wave;  // this wave's first row (in batch)

    __shared__ float sbuf[4 * 2048];   // per-wave slice: 2 bufs x 1 row x 1024 floats
    __shared__ unsigned int ticket_s;
    float* slice = &sbuf[wv << 11];

    // W fragment: lane l holds w[k*256 + l*4 .. +3]
    const float4* w4 = (const float4*)w;
    const float4 wf0 = w4[lane];
    const float4 wf1 = w4[lane + 64];
    const float4 wf2 = w4[lane + 128];
    const float4 wf3 = w4[lane + 192];

    // bias for this wave's rows, one per lane
    float biasv = 0.f;
    if (lane < rows_wave) biasv = bias[r0 + lane];

    const float* xb = x + (size_t)b * T * 1024;

    float4 acc0 = {0,0,0,0}, acc1 = {0,0,0,0}, acc2 = {0,0,0,0}, acc3 = {0,0,0,0};
    float lsum = 0.f;

#define ISSUE(gg) do {                                                          \
    const float* _src = xb + (size_t)(r0 + (gg)) * 1024 + (lane << 2);          \
    float* _dst = slice + (((gg) & 1) << 10);                                   \
    __builtin_amdgcn_global_load_lds((gas_ptr)(_src),       (las_ptr)(_dst),       16, 0, 0); \
    __builtin_amdgcn_global_load_lds((gas_ptr)(_src + 256), (las_ptr)(_dst + 256), 16, 0, 0); \
    __builtin_amdgcn_global_load_lds((gas_ptr)(_src + 512), (las_ptr)(_dst + 512), 16, 0, 0); \
    __builtin_amdgcn_global_load_lds((gas_ptr)(_src + 768), (las_ptr)(_dst + 768), 16, 0, 0); \
} while (0)

#define COMPUTE(gg) do {                                                        \
    const float* _s = slice + (((gg) & 1) << 10) + (lane << 2);                 \
    float4 a0 = *(const float4*)(_s);                                           \
    float4 a1 = *(const float4*)(_s + 256);                                     \
    float4 a2 = *(const float4*)(_s + 512);                                     \
    float4 a3 = *(const float4*)(_s + 768);                                     \
    float d = a0.x*wf0.x + a0.y*wf0.y + a0.z*wf0.z + a0.w*wf0.w;                \
    d += a1.x*wf1.x + a1.y*wf1.y + a1.z*wf1.z + a1.w*wf1.w;                     \
    d += a2.x*wf2.x + a2.y*wf2.y + a2.z*wf2.z + a2.w*wf2.w;                     \
    d += a3.x*wf3.x + a3.y*wf3.y + a3.z*wf3.z + a3.w*wf3.w;                     \
    _Pragma("unroll")                                                           \
    for (int off = 1; off < 64; off <<= 1) d += __shfl_xor(d, off);             \
    float e = __expf(tanhf(d + __shfl(biasv, (gg))));                           \
    lsum += e;                                                                  \
    acc0.x += e * a0.x; acc0.y += e * a0.y; acc0.z += e * a0.z; acc0.w += e * a0.w; \
    acc1.x += e * a1.x; acc1.y += e * a1.y; acc1.z += e * a1.z; acc1.w += e * a1.w; \
    acc2.x += e * a2.x; acc2.y += e * a2.y; acc2.z += e * a2.z; acc2.w += e * a2.w; \
    acc3.x += e * a3.x; acc3.y += e * a3.y; acc3.z += e * a3.z; acc3.w += e * a3.w; \
} while (0)

    ISSUE(0);
    for (int g = 0; g < rows_wave - 1; ++g) {
        ISSUE(g + 1);
        asm volatile("s_waitcnt vmcnt(4)" ::: "memory");   // current row arrived; next stays in flight
        __builtin_amdgcn_sched_barrier(0);
        COMPUTE(g);
    }
    asm volatile("s_waitcnt vmcnt(0)" ::: "memory");
    __builtin_amdgcn_sched_barrier(0);
    COMPUTE(rows_wave - 1);

#undef ISSUE
#undef COMPUTE

    // each wave writes its own partial: idx = (b*C + c)*4 + wv
    float* p = partials + (size_t)(((b * C + c) << 2) + wv) * PSTR;
    if (lane == 0) p[0] = lsum;      // lsum is lane-uniform (e uniform post-butterfly)
    float4* p4 = (float4*)(p + 8);   // float4 slot k*64+lane holds d = 4*(k*64+lane) -> d-linear
    p4[lane]       = acc0;
    p4[lane + 64]  = acc1;
    p4[lane + 128] = acc2;
    p4[lane + 192] = acc3;

    // last block of this batch combines
    __threadfence();
    __syncthreads();
    if (tid == 0) ticket_s = atomicAdd(&counters[b], 1u);
    __syncthreads();
    if (ticket_s == (unsigned)(C - 1)) {
        __threadfence();
        float L = 0.f;
        float4 s = {0.f, 0.f, 0.f, 0.f};
        const int nP = C << 2;
        for (int j = 0; j < nP; ++j) {
            const float* q = partials + (size_t)((b * C) * 4 + j) * PSTR;
            L += q[0];
            float4 a = ((const float4*)(q + 8))[tid];
            s.x += a.x; s.y += a.y; s.z += a.z; s.w += a.w;
        }
        float inv = 1.f / L;
        float4 r; r.x = s.x * inv; r.y = s.y * inv; r.z = s.z * inv; r.w = s.w * inv;
        ((float4*)out)[(b << 8) + tid] = r;
    }
}

extern "C" void kernel_launch(void* const* d_in, const int* in_sizes, int n_in,
                              void* d_out, int out_size, void* d_ws, size_t ws_size,
                              hipStream_t stream) {
    const float* x    = (const float*)d_in[0];   // [B,T,D]
    const float* w    = (const float*)d_in[1];   // [D,1]
    const float* bias = (const float*)d_in[2];   // [T,1]
    float* out = (float*)d_out;

    int D = in_sizes[1];            // 1024
    int T = in_sizes[2];            // 2048
    int nrows = in_sizes[0] / D;    // B*T
    int B = nrows / T;              // 32

    int C = T / 64;                 // 64 rows per block -> 16 per wave

    float* partials = (float*)d_ws;
    size_t part_bytes = (size_t)B * C * 4 * PSTR * sizeof(float);
    unsigned int* counters = (unsigned int*)((char*)d_ws + part_bytes);

    hipMemsetAsync(counters, 0, B * sizeof(unsigned int), stream);
    fused_all<<<dim3(C, B), 256, 0, stream>>>(x, w, bias, partials, counters, out, T, C);
}

// Round 5
// 59.488 us; speedup vs baseline: 4.0618x; 4.0618x over previous
//
#include <hip/hip_runtime.h>

// B=32, T=2048, D=1024 (fp32)
// out[b,d] = sum_t softmax_t(tanh(x[b,t,:]·W + bias[t])) * x[b,t,d]
// tanh in (-1,1) -> exp never overflows -> single pass, no max subtraction.
//
// Round-5: two kernels, NO device fences / tickets (rounds 3-4 post-mortem:
// per-block __threadfence (buffer_wbl2/inv sc1) x 1024 blocks serialized the
// memory system -> 300us dispatches regardless of loop body). Main loop is a
// fully-unrolled register ping-pong (all buf indices compile-time constant).

#define PSTR 1032  // floats per partial: [0]=lsum, [8..1032)=acc[1024]

__global__ __launch_bounds__(256) void fused_main(
    const float* __restrict__ x, const float* __restrict__ w,
    const float* __restrict__ bias, float* __restrict__ partials,
    int T, int C)
{
    const int c = blockIdx.x;      // T-chunk (64 rows)
    const int b = blockIdx.y;      // batch
    const int wv = threadIdx.x >> 6;
    const int lane = threadIdx.x & 63;
    const int tid = threadIdx.x;

    const int rows_block = T / C;              // 64
    const int rows_wave  = rows_block >> 2;    // 16
    const int r0 = c * rows_block + wv * rows_wave;

    // W fragment: lane l holds w[k*256 + l*4 .. +3]
    const float4* w4 = (const float4*)w;
    const float4 wf0 = w4[lane];
    const float4 wf1 = w4[lane + 64];
    const float4 wf2 = w4[lane + 128];
    const float4 wf3 = w4[lane + 192];

    // bias for this wave's 16 rows, one per lane
    float biasv = (lane < rows_wave) ? bias[r0 + lane] : 0.f;

    const float4* xr0 = (const float4*)x + ((size_t)b * T + r0) * 256 + lane;

    float4 acc0 = {0,0,0,0}, acc1 = {0,0,0,0}, acc2 = {0,0,0,0}, acc3 = {0,0,0,0};
    float lsum = 0.f;

    float4 buf[2][4];  // ping-pong; indexed ONLY by constants after unroll

#define LOADG(gg) do {                                   \
    const float4* _p = xr0 + (size_t)(gg) * 256;         \
    buf[(gg) & 1][0] = _p[0];                            \
    buf[(gg) & 1][1] = _p[64];                           \
    buf[(gg) & 1][2] = _p[128];                          \
    buf[(gg) & 1][3] = _p[192];                          \
} while (0)

#define COMPUTEG(gg) do {                                                     \
    float4 a0 = buf[(gg) & 1][0], a1 = buf[(gg) & 1][1];                      \
    float4 a2 = buf[(gg) & 1][2], a3 = buf[(gg) & 1][3];                      \
    float d = a0.x*wf0.x + a0.y*wf0.y + a0.z*wf0.z + a0.w*wf0.w;              \
    d += a1.x*wf1.x + a1.y*wf1.y + a1.z*wf1.z + a1.w*wf1.w;                   \
    d += a2.x*wf2.x + a2.y*wf2.y + a2.z*wf2.z + a2.w*wf2.w;                   \
    d += a3.x*wf3.x + a3.y*wf3.y + a3.z*wf3.z + a3.w*wf3.w;                   \
    _Pragma("unroll")                                                         \
    for (int off = 1; off < 64; off <<= 1) d += __shfl_xor(d, off);           \
    float _a = d + __shfl(biasv, (gg));                                       \
    float _t = 1.f - 2.f / (__expf(2.f * _a) + 1.f);   /* tanh, inf-safe */   \
    float e = __expf(_t);                                                     \
    lsum += e;                                                                \
    acc0.x += e*a0.x; acc0.y += e*a0.y; acc0.z += e*a0.z; acc0.w += e*a0.w;   \
    acc1.x += e*a1.x; acc1.y += e*a1.y; acc1.z += e*a1.z; acc1.w += e*a1.w;   \
    acc2.x += e*a2.x; acc2.y += e*a2.y; acc2.z += e*a2.z; acc2.w += e*a2.w;   \
    acc3.x += e*a3.x; acc3.y += e*a3.y; acc3.z += e*a3.z; acc3.w += e*a3.w;   \
} while (0)

    LOADG(0);
#pragma unroll
    for (int g = 0; g < 16; ++g) {   // rows_wave == 16 (host guarantees)
        if (g < 15) LOADG(g + 1);    // next row always in flight during compute
        COMPUTEG(g);
    }

#undef LOADG
#undef COMPUTEG

    // combine 4 waves via LDS -> one partial per block
    __shared__ float lacc[4 * 1024];
    __shared__ float lls[4];
    float4* lacc4 = (float4*)lacc;
    lacc4[wv * 256 + lane]       = acc0;
    lacc4[wv * 256 + 64 + lane]  = acc1;
    lacc4[wv * 256 + 128 + lane] = acc2;
    lacc4[wv * 256 + 192 + lane] = acc3;
    if (lane == 0) lls[wv] = lsum;
    __syncthreads();

    float4 o0 = lacc4[tid];
    float4 o1 = lacc4[256 + tid];
    float4 o2 = lacc4[512 + tid];
    float4 o3 = lacc4[768 + tid];
    float4 o;
    o.x = (o0.x + o1.x) + (o2.x + o3.x);
    o.y = (o0.y + o1.y) + (o2.y + o3.y);
    o.z = (o0.z + o1.z) + (o2.z + o3.z);
    o.w = (o0.w + o1.w) + (o2.w + o3.w);

    float* p = partials + (size_t)(b * C + c) * PSTR;
    if (tid == 0) p[0] = (lls[0] + lls[1]) + (lls[2] + lls[3]);
    ((float4*)(p + 8))[tid] = o;
}

__global__ __launch_bounds__(256) void combine_kernel(
    const float* __restrict__ partials, float* __restrict__ out, int C)
{
    const int b = blockIdx.x;
    const int tid = threadIdx.x;
    float L = 0.f;
    float4 o = {0.f, 0.f, 0.f, 0.f};
    for (int c = 0; c < C; ++c) {
        const float* p = partials + (size_t)(b * C + c) * PSTR;
        L += p[0];
        float4 a = ((const float4*)(p + 8))[tid];
        o.x += a.x; o.y += a.y; o.z += a.z; o.w += a.w;
    }
    float inv = 1.f / L;
    float4 r; r.x = o.x * inv; r.y = o.y * inv; r.z = o.z * inv; r.w = o.w * inv;
    ((float4*)out)[b * 256 + tid] = r;
}

extern "C" void kernel_launch(void* const* d_in, const int* in_sizes, int n_in,
                              void* d_out, int out_size, void* d_ws, size_t ws_size,
                              hipStream_t stream) {
    const float* x    = (const float*)d_in[0];   // [B,T,D]
    const float* w    = (const float*)d_in[1];   // [D,1]
    const float* bias = (const float*)d_in[2];   // [T,1]
    float* out = (float*)d_out;

    int D = in_sizes[1];            // 1024
    int T = in_sizes[2];            // 2048
    int nrows = in_sizes[0] / D;    // B*T
    int B = nrows / T;              // 32

    int C = T / 64;                 // 64 rows per block -> 16 per wave

    float* partials = (float*)d_ws;

    fused_main<<<dim3(C, B), 256, 0, stream>>>(x, w, bias, partials, T, C);
    combine_kernel<<<B, 256, 0, stream>>>(partials, out, C);
}

// Round 6
// 53.087 us; speedup vs baseline: 4.5515x; 1.1206x over previous
//
#include <hip/hip_runtime.h>

// B=32, T=2048, D=1024 (fp32)
// out[b,d] = sum_t softmax_t(tanh(x[b,t,:]·W + bias[t])) * x[b,t,d]
// tanh in (-1,1) -> exp never overflows -> single pass, no max subtraction.
//
// R6: R5's proven structure (no fences/tickets - those cost 5x in R3/R4), plus:
//  - 2-row-deep register prefetch (3-slot rotation, compile-time indices only)
//  - combine kernel unrolled x4 (independent chains -> loads overlap)

#define PSTR 1032  // floats per partial: [0]=lsum, [8..1032)=acc[1024]

__global__ __launch_bounds__(256) void fused_main(
    const float* __restrict__ x, const float* __restrict__ w,
    const float* __restrict__ bias, float* __restrict__ partials,
    int T, int C)
{
    const int c = blockIdx.x;      // T-chunk (64 rows)
    const int b = blockIdx.y;      // batch
    const int wv = threadIdx.x >> 6;
    const int lane = threadIdx.x & 63;
    const int tid = threadIdx.x;

    const int rows_block = T / C;              // 64
    const int rows_wave  = rows_block >> 2;    // 16
    const int r0 = c * rows_block + wv * rows_wave;

    // W fragment: lane l holds w[k*256 + l*4 .. +3]
    const float4* w4 = (const float4*)w;
    const float4 wf0 = w4[lane];
    const float4 wf1 = w4[lane + 64];
    const float4 wf2 = w4[lane + 128];
    const float4 wf3 = w4[lane + 192];

    // bias for this wave's 16 rows, one per lane
    float biasv = (lane < rows_wave) ? bias[r0 + lane] : 0.f;

    const float4* xr0 = (const float4*)x + ((size_t)b * T + r0) * 256 + lane;

    float4 acc0 = {0,0,0,0}, acc1 = {0,0,0,0}, acc2 = {0,0,0,0}, acc3 = {0,0,0,0};
    float lsum = 0.f;

    float4 buf[3][4];  // 3-slot rotation; indexed ONLY by constants after unroll

#define LOADG(gg) do {                                   \
    const float4* _p = xr0 + (size_t)(gg) * 256;         \
    buf[(gg) % 3][0] = _p[0];                            \
    buf[(gg) % 3][1] = _p[64];                           \
    buf[(gg) % 3][2] = _p[128];                          \
    buf[(gg) % 3][3] = _p[192];                          \
} while (0)

#define COMPUTEG(gg) do {                                                     \
    float4 a0 = buf[(gg) % 3][0], a1 = buf[(gg) % 3][1];                      \
    float4 a2 = buf[(gg) % 3][2], a3 = buf[(gg) % 3][3];                      \
    float d = a0.x*wf0.x + a0.y*wf0.y + a0.z*wf0.z + a0.w*wf0.w;              \
    d += a1.x*wf1.x + a1.y*wf1.y + a1.z*wf1.z + a1.w*wf1.w;                   \
    d += a2.x*wf2.x + a2.y*wf2.y + a2.z*wf2.z + a2.w*wf2.w;                   \
    d += a3.x*wf3.x + a3.y*wf3.y + a3.z*wf3.z + a3.w*wf3.w;                   \
    _Pragma("unroll")                                                         \
    for (int off = 1; off < 64; off <<= 1) d += __shfl_xor(d, off);           \
    float _a = d + __shfl(biasv, (gg));                                       \
    float _t = 1.f - 2.f / (__expf(2.f * _a) + 1.f);   /* tanh, inf-safe */   \
    float e = __expf(_t);                                                     \
    lsum += e;                                                                \
    acc0.x += e*a0.x; acc0.y += e*a0.y; acc0.z += e*a0.z; acc0.w += e*a0.w;   \
    acc1.x += e*a1.x; acc1.y += e*a1.y; acc1.z += e*a1.z; acc1.w += e*a1.w;   \
    acc2.x += e*a2.x; acc2.y += e*a2.y; acc2.z += e*a2.z; acc2.w += e*a2.w;   \
    acc3.x += e*a3.x; acc3.y += e*a3.y; acc3.z += e*a3.z; acc3.w += e*a3.w;   \
} while (0)

    LOADG(0);
    LOADG(1);
#pragma unroll
    for (int g = 0; g < 16; ++g) {   // rows_wave == 16 (host guarantees)
        if (g < 14) LOADG(g + 2);    // two rows always in flight during compute
        COMPUTEG(g);
    }

#undef LOADG
#undef COMPUTEG

    // combine 4 waves via LDS -> one partial per block
    __shared__ float lacc[4 * 1024];
    __shared__ float lls[4];
    float4* lacc4 = (float4*)lacc;
    lacc4[wv * 256 + lane]       = acc0;
    lacc4[wv * 256 + 64 + lane]  = acc1;
    lacc4[wv * 256 + 128 + lane] = acc2;
    lacc4[wv * 256 + 192 + lane] = acc3;
    if (lane == 0) lls[wv] = lsum;
    __syncthreads();

    float4 o0 = lacc4[tid];
    float4 o1 = lacc4[256 + tid];
    float4 o2 = lacc4[512 + tid];
    float4 o3 = lacc4[768 + tid];
    float4 o;
    o.x = (o0.x + o1.x) + (o2.x + o3.x);
    o.y = (o0.y + o1.y) + (o2.y + o3.y);
    o.z = (o0.z + o1.z) + (o2.z + o3.z);
    o.w = (o0.w + o1.w) + (o2.w + o3.w);

    float* p = partials + (size_t)(b * C + c) * PSTR;
    if (tid == 0) p[0] = (lls[0] + lls[1]) + (lls[2] + lls[3]);
    ((float4*)(p + 8))[tid] = o;
}

__global__ __launch_bounds__(256) void combine_kernel(
    const float* __restrict__ partials, float* __restrict__ out, int C)
{
    const int b = blockIdx.x;
    const int tid = threadIdx.x;

    float L0 = 0.f, L1 = 0.f, L2 = 0.f, L3 = 0.f;
    float4 o0 = {0,0,0,0}, o1 = {0,0,0,0}, o2 = {0,0,0,0}, o3 = {0,0,0,0};

    int c = 0;
    for (; c + 4 <= C; c += 4) {
        const float* p0 = partials + (size_t)(b * C + c) * PSTR;
        const float* p1 = p0 + PSTR;
        const float* p2 = p1 + PSTR;
        const float* p3 = p2 + PSTR;
        float l0 = p0[0], l1 = p1[0], l2 = p2[0], l3 = p3[0];
        float4 a0 = ((const float4*)(p0 + 8))[tid];
        float4 a1 = ((const float4*)(p1 + 8))[tid];
        float4 a2 = ((const float4*)(p2 + 8))[tid];
        float4 a3 = ((const float4*)(p3 + 8))[tid];
        L0 += l0; L1 += l1; L2 += l2; L3 += l3;
        o0.x += a0.x; o0.y += a0.y; o0.z += a0.z; o0.w += a0.w;
        o1.x += a1.x; o1.y += a1.y; o1.z += a1.z; o1.w += a1.w;
        o2.x += a2.x; o2.y += a2.y; o2.z += a2.z; o2.w += a2.w;
        o3.x += a3.x; o3.y += a3.y; o3.z += a3.z; o3.w += a3.w;
    }
    for (; c < C; ++c) {
        const float* p = partials + (size_t)(b * C + c) * PSTR;
        L0 += p[0];
        float4 a = ((const float4*)(p + 8))[tid];
        o0.x += a.x; o0.y += a.y; o0.z += a.z; o0.w += a.w;
    }

    float L = (L0 + L1) + (L2 + L3);
    float4 o;
    o.x = (o0.x + o1.x) + (o2.x + o3.x);
    o.y = (o0.y + o1.y) + (o2.y + o3.y);
    o.z = (o0.z + o1.z) + (o2.z + o3.z);
    o.w = (o0.w + o1.w) + (o2.w + o3.w);
    float inv = 1.f / L;
    float4 r; r.x = o.x * inv; r.y = o.y * inv; r.z = o.z * inv; r.w = o.w * inv;
    ((float4*)out)[b * 256 + tid] = r;
}

extern "C" void kernel_launch(void* const* d_in, const int* in_sizes, int n_in,
                              void* d_out, int out_size, void* d_ws, size_t ws_size,
                              hipStream_t stream) {
    const float* x    = (const float*)d_in[0];   // [B,T,D]
    const float* w    = (const float*)d_in[1];   // [D,1]
    const float* bias = (const float*)d_in[2];   // [T,1]
    float* out = (float*)d_out;

    int D = in_sizes[1];            // 1024
    int T = in_sizes[2];            // 2048
    int nrows = in_sizes[0] / D;    // B*T
    int B = nrows / T;              // 32

    int C = T / 64;                 // 64 rows per block -> 16 per wave

    float* partials = (float*)d_ws;

    fused_main<<<dim3(C, B), 256, 0, stream>>>(x, w, bias, partials, T, C);
    combine_kernel<<<B, 256, 0, stream>>>(partials, out, C);
}